// Round 22
// baseline (133.948 us; speedup 1.0000x reference)
//
#include <hip/hip_runtime.h>

#define NBOX 300000
#define NFEAT 85
#define NCLS 80
#define NBUCK 4096
#define HSPLIT 16
#define CMAX 8192
#define W64 (CMAX / 64)   // 128 kept-mask words (finalize bookkeeping)
#define MAXKEEP 1000
#define SC_ROWS 64        // k_scores tile rows

typedef unsigned long long u64;
typedef float f4a __attribute__((ext_vector_type(4), aligned(16)));

__device__ __forceinline__ int bucket_of(float s) {
    int b = (int)((s - 0.3f) * (4096.0f / 0.7f));
    if (b < 0) b = 0;
    if (b > NBUCK - 1) b = NBUCK - 1;
    return b;
}

__device__ __forceinline__ bool sup_iou(float by1, float bx1, float by2, float bx2, float ba,
                                        float y1, float x1, float y2, float x2, float area) {
    float iy1 = fmaxf(by1, y1), ix1 = fmaxf(bx1, x1);
    float iy2 = fminf(by2, y2), ix2 = fminf(bx2, x2);
    float inter = fmaxf(iy2 - iy1, 0.0f) * fmaxf(ix2 - ix1, 0.0f);
    float uni = ba + area - inter;
    float iou = (uni > 0.0f) ? inter / uni : 0.0f;
    return iou > 0.5f;
}

__global__ void k_init(unsigned* __restrict__ hist16, unsigned* __restrict__ cnt,
                       int* __restrict__ meta) {
    int i = blockIdx.x * blockDim.x + threadIdx.x;
    if (i < HSPLIT * NBUCK) hist16[i] = 0u;
    if (i < NBUCK) cnt[i] = 0u;
    if (i < 16) meta[i] = 0;
}

// Coalesced staged scores + 16-way split histograms (R21-proven DMA staging;
// tail 64 floats now also via width-4 DMA, wave 0). No completion protocol:
// R16-R20 proved in-kernel multi-writer completion costs ~+35us; blocks exit
// with atomics in flight, kernel boundary orders them.
__global__ void __launch_bounds__(256) k_scores(const float* __restrict__ in,
        float* __restrict__ scores, unsigned* __restrict__ hist16) {
    __shared__ float lds[SC_ROWS * NFEAT];  // 21760 B
    int t = threadIdx.x;
    int lane = t & 63, wv = t >> 6;
    long long rbase = (long long)blockIdx.x * SC_ROWS;
    int rows = (NBOX - rbase < SC_ROWS) ? (int)(NBOX - rbase) : SC_ROWS;
    if (rows == SC_ROWS) {
        const float* src = in + rbase * NFEAT;  // 21760*b bytes: 16B-aligned
        for (int k = wv; k < 21; k += 4)
            __builtin_amdgcn_global_load_lds(
                (const __attribute__((address_space(1))) void*)(src + k * 256 + lane * 4),
                (__attribute__((address_space(3))) void*)&lds[k * 256], 16, 0, 0);
        if (wv == 0)  // tail 64 floats: one width-4 DMA (lane*4B)
            __builtin_amdgcn_global_load_lds(
                (const __attribute__((address_space(1))) void*)(src + 5376 + lane),
                (__attribute__((address_space(3))) void*)&lds[5376], 4, 0, 0);
    } else {
        int nfl = rows * NFEAT;
        int nf4 = nfl >> 2;
        const f4a* src4 = (const f4a*)(in + rbase * NFEAT);
        f4a* dst = (f4a*)lds;
        for (int k = t; k < nf4; k += 256) dst[k] = src4[k];
        for (int k = (nf4 << 2) + t; k < nfl; k += 256) lds[k] = in[rbase * NFEAT + k];
    }
    __syncthreads();  // also drains the DMA (vmcnt)
    unsigned* myhist = hist16 + (size_t)(blockIdx.x & (HSPLIT - 1)) * NBUCK;
    int row = t >> 2, part = t & 3;
    if (row < rows) {
        const float* r = lds + row * NFEAT;
        const float* p = r + 5 + 20 * part;
        float mx = p[0];
        #pragma unroll
        for (int j = 1; j < 20; ++j) mx = fmaxf(mx, p[j]);
        mx = fmaxf(mx, __shfl_xor(mx, 1));
        mx = fmaxf(mx, __shfl_xor(mx, 2));
        if (part == 0) {
            float best = r[4] * mx;  // == max(conf*p) exactly (conf>=0, RN monotone)
            scores[rbase + row] = best;
            if (best >= 0.3f) atomicAdd(&myhist[bucket_of(best)], 1u);
        }
    }
}

// Scatter with REDUNDANT per-block thresh (zero inter-block sync — the R16-R20
// lesson: completion protocols cost more than recompute). Every block reads the
// final hist16 (kernel boundary guarantees completeness), computes bucket
// suffix-sums + bstar + off[] in LDS (~2-3us, L2-resident, all 1172 blocks
// co-resident so wall cost is paid once), then scatters. Block 0 publishes
// histsum/off/meta for k_rank (kernel-boundary visibility).
__global__ void __launch_bounds__(256) k_scatter(const float* __restrict__ scores,
        const unsigned* __restrict__ hist16, unsigned* __restrict__ histsum,
        unsigned* __restrict__ off_g, int* __restrict__ meta,
        unsigned* __restrict__ cnt, u64* __restrict__ unsorted) {
    __shared__ unsigned off_lds[NBUCK];  // 16 KB
    __shared__ unsigned chunk[256];
    __shared__ int sh_bstar;
    int t = threadIdx.x;
    // ---- thresh (R16-proven 256-thread code, per-block local) ----
    unsigned h[16];
    unsigned s = 0;
    #pragma unroll
    for (int j = 0; j < 16; ++j) {
        int b = t * 16 + j;
        unsigned v = 0;
        for (int g = 0; g < HSPLIT; ++g) v += hist16[g * NBUCK + b];
        h[j] = v; s += v;
    }
    chunk[t] = s;
    __syncthreads();
    for (int o = 1; o < 256; o <<= 1) {
        unsigned add = (t + o < 256) ? chunk[t + o] : 0u;
        __syncthreads();
        chunk[t] += add;
        __syncthreads();
    }
    unsigned after = (t + 1 < 256) ? chunk[t + 1] : 0u;
    unsigned suf[17];
    suf[16] = after;
    #pragma unroll
    for (int j = 15; j >= 0; --j) suf[j] = suf[j + 1] + h[j];
    #pragma unroll
    for (int j = 0; j < 16; ++j) {
        int b = t * 16 + j;
        off_lds[b] = suf[j + 1];
        unsigned sufb = suf[j], sufprev;
        if (b == 0) sufprev = 0xFFFFFFFFu;
        else if (j > 0) sufprev = suf[j - 1];
        else {
            unsigned hprev = 0;
            for (int g = 0; g < HSPLIT; ++g) hprev += hist16[g * NBUCK + b - 1];
            sufprev = sufb + hprev;
        }
        if (sufb <= (unsigned)CMAX && sufprev > (unsigned)CMAX) {  // unique b
            sh_bstar = b;
            if (blockIdx.x == 0) { meta[1] = b; meta[0] = (int)sufb; }
        }
    }
    if (blockIdx.x == 0) {  // publish for k_rank (kernel-boundary visibility)
        #pragma unroll
        for (int j = 0; j < 16; ++j) {
            int b = t * 16 + j;
            histsum[b] = h[j];
            off_g[b] = suf[j + 1];
        }
    }
    __syncthreads();
    int bstar = sh_bstar;
    // ---- scatter ----
    int i = blockIdx.x * blockDim.x + t;
    if (i < NBOX) {
        float sc = scores[i];
        if (sc >= 0.3f) {
            int b = bucket_of(sc);
            if (b >= bstar) {
                unsigned slot = off_lds[b] + atomicAdd(&cnt[b], 1u);
                if (slot < CMAX)
                    unsorted[slot] = ((u64)__float_as_uint(sc) << 32) |
                                     (u64)(0xFFFFFFFFu - (unsigned)i);
            }
        }
    }
}

// Exact rank within bucket -> fully sorted, deterministic (MULTI-BLOCK: the
// per-candidate bucket-scan loads need cross-CU TLP — R16's 1-block fusion of
// this phase was a 10x regression). Compacts box + validity flag per slot.
__global__ void k_rank(const float* __restrict__ in, const u64* __restrict__ unsorted,
                       const unsigned* __restrict__ off, const unsigned* __restrict__ histsum,
                       const int* __restrict__ meta, u64* __restrict__ sorted,
                       float4* __restrict__ boxes4, unsigned* __restrict__ vflag) {
    int i = blockIdx.x * blockDim.x + threadIdx.x;
    int total = meta[0];
    if (i >= total) return;
    u64 k = unsorted[i];
    float s = __uint_as_float((unsigned)(k >> 32));
    int b = bucket_of(s);
    unsigned base = off[b];
    unsigned n = histsum[b];
    unsigned r = 0;
    for (unsigned u = 0; u < n; ++u) r += (unsorted[base + u] > k) ? 1u : 0u;
    int bi = (int)(0xFFFFFFFFu - (unsigned)(k & 0xFFFFFFFFull));
    const float* p = in + (size_t)bi * NFEAT;
    float4 bx = make_float4(p[0], p[1], p[2], p[3]);  // y1,x1,y2,x2
    sorted[base + r] = k;
    boxes4[base + r] = bx;
    vflag[base + r] = (bx.z > bx.x && bx.w > bx.y) ? 1u : 0u;
}

// Fused NMS (R15 structure — proven):
//  - vscan & finalize use WAVE-LEVEL scans (shfl_up, 2 barriers each)
//  - sweep greedy is Z-GATED: zero-col candidates (suppress nobody) batch-kept
//    in one mask op; serial iterations only for the ~1/block nonzero-col keeps.
// Degenerate boxes (IoU==0 with everything) skip the sweep, always kept.
__global__ void __launch_bounds__(1024) k_nms(const float4* __restrict__ boxes4,
        const unsigned* __restrict__ vflag, int* __restrict__ meta,
        unsigned* __restrict__ vincl, unsigned* __restrict__ cmap,
        float4* __restrict__ cboxes, int* __restrict__ kfinal) {
    __shared__ float4 klist[MAXKEEP + 64];
    __shared__ u64 colmask[64];
    __shared__ u64 pf[16];
    __shared__ u64 vkeptw[W64];
    __shared__ unsigned wsum[16];
    __shared__ int sh_nkept, sh_wlim, sh_stop;
    int t = threadIdx.x;
    int lane = t & 63, wv = t >> 6;
    int total = meta[0];

    if (t < W64) vkeptw[t] = 0ull;
    if (t == 0) { sh_nkept = 0; sh_wlim = 0; sh_stop = 0; }

    // ---- vscan phase (wave-level scan: 2 barriers) ----
    unsigned f[8];
    {
        unsigned run = 0;
        #pragma unroll
        for (int e = 0; e < 8; ++e) {
            int s = t * 8 + e;
            unsigned v = (s < total) ? vflag[s] : 0u;
            run += v;
            f[e] = run;
        }
        unsigned wx = run;
        #pragma unroll
        for (int o = 1; o < 64; o <<= 1) {
            unsigned u = __shfl_up(wx, o);
            if (lane >= o) wx += u;
        }
        if (lane == 63) wsum[wv] = wx;
        __syncthreads();
        if (t < 16) {
            unsigned v = wsum[t];
            #pragma unroll
            for (int o = 1; o < 16; o <<= 1) {
                unsigned u = __shfl_up(v, o);
                if (t >= o) v += u;
            }
            wsum[t] = v;
        }
        __syncthreads();
        unsigned base = ((wv > 0) ? wsum[wv - 1] : 0u) + (wx - run);
        #pragma unroll
        for (int e = 0; e < 8; ++e) {
            int s = t * 8 + e;
            unsigned incl = base + f[e];
            vincl[s] = incl;
            if (s < total && vflag[s]) {
                cmap[incl - 1] = (unsigned)s;
                cboxes[incl - 1] = boxes4[s];
            }
        }
    }
    int nv = (int)wsum[15];
    if (t == 0) meta[3] = nv;
    int nblkv = (nv + 63) >> 6;
    __syncthreads();  // cboxes/cmap visible before sweep

    // ---- sweep phase (16-wave prefilter + col build; Z-gated wave-0 greedy) ----
    for (int w = 0; w < nblkv; ++w) {
        int base = w << 6;
        int c = base + lane;
        float4 mb = (c < nv) ? cboxes[c] : make_float4(0.f, 0.f, 0.f, 0.f);
        float marea = (mb.z - mb.x) * (mb.w - mb.y);
        int cend = (base + 63 < nv - 1) ? (base + 63) : (nv - 1);
        unsigned cm = 0;
        if (wv == 0) cm = cmap[cend];  // issued early, used after barrier
        int nk = sh_nkept;  // stable: post prior-iteration barrier
        // A) prefilter: wave wv covers klist[wv::16]
        bool ok = true;
        for (int k = wv; k < nk; k += 16) {
            float4 b = klist[k];
            float ba = (b.z - b.x) * (b.w - b.y);
            if (sup_iou(b.x, b.y, b.z, b.w, ba, mb.x, mb.y, mb.z, mb.w, marea))
                ok = false;
        }
        u64 pv = __ballot(ok ? 1 : 0);
        if (lane == 0) pf[wv] = pv;
        // B) intra-block cols: wave wv builds rows 4*wv .. 4*wv+3
        #pragma unroll
        for (int r = 0; r < 4; ++r) {
            int i = wv * 4 + r;
            int ii = (base + i < nv) ? (base + i) : 0;  // clamp; garbage cols of
            float4 bi = cboxes[ii];                     // dead rows are never used
            float ba = (bi.z - bi.x) * (bi.w - bi.y);
            bool s = (lane > i) &&
                     sup_iou(bi.x, bi.y, bi.z, bi.w, ba, mb.x, mb.y, mb.z, mb.w, marea);
            u64 bm = __ballot(s ? 1 : 0);
            if (lane == 0) colmask[i] = bm;
        }
        __syncthreads();
        // C) wave 0: Z-gated greedy (zero-col candidates suppress nobody ->
        // batch-kept below the lowest nonzero-col candidate; exact)
        if (wv == 0) {
            int rc = nv - base;
            u64 vm = (rc >= 64) ? ~0ull : ((1ull << rc) - 1ull);
            u64 aliveM = vm;
            #pragma unroll
            for (int q = 0; q < 16; ++q) aliveM &= pf[q];
            u64 col = colmask[lane];
            u64 nzc = __ballot(col != 0ull);
            u64 remaining = aliveM, keptM = 0ull;
            while (remaining) {
                u64 hard = remaining & nzc;
                if (!hard) { keptM |= remaining; break; }
                int ih = __ffsll(hard) - 1;
                u64 below = remaining & ((1ull << ih) - 1ull);  // all zero-col
                keptM |= below | (1ull << ih);
                remaining &= ~(below | (1ull << ih));
                u64 ci = __shfl(col, ih);
                remaining &= ~ci;
            }
            int nk0 = sh_nkept;
            if ((keptM >> lane) & 1ull) {
                int rank = __popcll(keptM & ((1ull << lane) - 1ull));
                klist[nk0 + rank] = mb;
            }
            if (lane == 0) {
                int kp = __popcll(keptM);
                vkeptw[w] = keptM;
                sh_nkept = nk0 + kp;
                sh_wlim = w + 1;
                // merged kept through slot cm: invalids (cm-cend) + valid-kept
                if ((int)cm - cend + nk0 + kp >= MAXKEEP) sh_stop = 1;
            }
        }
        __syncthreads();
        if (sh_stop) break;  // uniform
    }
    int wlim = sh_wlim;

    // ---- finalize (wave-level scan: 2 barriers) ----
    {
        unsigned run = 0;
        #pragma unroll
        for (int e = 0; e < 8; ++e) {
            int s = t * 8 + e;
            unsigned kept = 0u;
            if (s < total) {
                if (!vflag[s]) kept = 1u;
                else {
                    unsigned cc = vincl[s] - 1u;
                    int w = (int)(cc >> 6);
                    if (w < wlim && ((vkeptw[w] >> (cc & 63u)) & 1ull)) kept = 1u;
                }
            }
            run += kept;
            f[e] = run;
        }
        unsigned wx = run;
        #pragma unroll
        for (int o = 1; o < 64; o <<= 1) {
            unsigned u = __shfl_up(wx, o);
            if (lane >= o) wx += u;
        }
        __syncthreads();  // wsum reuse: vscan values dead
        if (lane == 63) wsum[wv] = wx;
        __syncthreads();
        if (t < 16) {
            unsigned v = wsum[t];
            #pragma unroll
            for (int o = 1; o < 16; o <<= 1) {
                unsigned u = __shfl_up(v, o);
                if (t >= o) v += u;
            }
            wsum[t] = v;
        }
        __syncthreads();
        unsigned base = ((wv > 0) ? wsum[wv - 1] : 0u) + (wx - run);
        #pragma unroll
        for (int e = 0; e < 8; ++e) {
            int s = t * 8 + e;
            unsigned kept = 0u;
            if (s < total) {
                if (!vflag[s]) kept = 1u;
                else {
                    unsigned cc = vincl[s] - 1u;
                    int w = (int)(cc >> 6);
                    if (w < wlim && ((vkeptw[w] >> (cc & 63u)) & 1ull)) kept = 1u;
                }
            }
            unsigned incl = base + f[e];
            if (kept && incl <= (unsigned)MAXKEEP) kfinal[incl - 1] = s;
        }
        if (t == 0) {
            unsigned tot = wsum[15];
            meta[2] = (int)(tot < (unsigned)MAXKEEP ? tot : (unsigned)MAXKEEP);
        }
    }
}

// One wave per output row (MULTI-BLOCK): butterfly argmax, strict-greater /
// lower-index tiebreak (== jnp.argmax first occurrence).
__global__ void __launch_bounds__(256) k_output(const float* __restrict__ in,
        const u64* __restrict__ gkeys, const int* __restrict__ meta,
        const int* __restrict__ kfinal, float* __restrict__ out) {
    int gw = (blockIdx.x * blockDim.x + threadIdx.x) >> 6;
    int lane = threadIdx.x & 63;
    if (gw >= MAXKEEP) return;
    int kc = meta[2];
    if (gw < kc) {
        int pos = kfinal[gw];
        u64 key = gkeys[pos];
        int bi = (int)(0xFFFFFFFFu - (unsigned)(key & 0xFFFFFFFFull));
        const float* row = in + (size_t)bi * NFEAT;
        float conf = row[4];
        float v0 = (lane < NCLS) ? conf * row[5 + lane] : -1.0f;
        float v1 = (lane < NCLS - 64) ? conf * row[5 + 64 + lane] : -1.0f;
        float bv = (v1 > v0) ? v1 : v0;
        int bix = (v1 > v0) ? (64 + lane) : lane;
        #pragma unroll
        for (int o = 1; o < 64; o <<= 1) {
            float ov = __shfl_xor(bv, o);
            int oi = __shfl_xor(bix, o);
            if (ov > bv || (ov == bv && oi < bix)) { bv = ov; bix = oi; }
        }
        float wv = 0.f;
        if (lane < 4) wv = row[lane];
        else if (lane == 4) wv = (float)bix;
        else wv = bv;
        if (lane < 6) out[gw * 6 + lane] = wv;
    } else {
        if (lane < 6) out[gw * 6 + lane] = 0.f;
    }
}

extern "C" void kernel_launch(void* const* d_in, const int* in_sizes, int n_in,
                              void* d_out, int out_size, void* d_ws, size_t ws_size,
                              hipStream_t stream) {
    const float* in = (const float*)d_in[0];
    float* out = (float*)d_out;
    char* ws = (char*)d_ws;
    // ws layout (bytes):
    //   [0, 65536)           sorted   u64[8192]
    //   [65536, 65600)       meta     i32[16] {0:total,1:bstar,2:kc,3:nvalid}
    //   [65600, 69696)       kfinal   i32[1024]
    //   [69696, 102464)      vflag    u32[8192]
    //   [102464, 135232)     vincl    u32[8192]
    //   [135232, 168000)     cmap     u32[8192]
    //   [168000, 300096)     cboxes   float4[8256]  (+64 pad)
    //   [300096, 431168)     boxes4   float4[8192]
    //   [431168, 1631168)    scores   f32[300000]
    //   [1631168, 1893312)   hist16   u32[16*4096]
    //   [1893312, 1909696)   histsum  u32[4096]
    //   [1909696, 1926080)   cnt      u32[4096]
    //   [1926080, 1942464)   off      u32[4096]
    //   [1942464, 2008000)   unsorted u64[8192]
    u64* sorted = (u64*)(ws);
    int* meta = (int*)(ws + 65536);
    int* kfinal = (int*)(ws + 65600);
    unsigned* vflag = (unsigned*)(ws + 69696);
    unsigned* vincl = (unsigned*)(ws + 102464);
    unsigned* cmap = (unsigned*)(ws + 135232);
    float4* cboxes = (float4*)(ws + 168000);
    float4* boxes4 = (float4*)(ws + 300096);
    float* scores = (float*)(ws + 431168);
    unsigned* hist16 = (unsigned*)(ws + 1631168);
    unsigned* histsum = (unsigned*)(ws + 1893312);
    unsigned* cnt = (unsigned*)(ws + 1909696);
    unsigned* off = (unsigned*)(ws + 1926080);
    u64* unsorted = (u64*)(ws + 1942464);

    k_init<<<dim3(256), dim3(256), 0, stream>>>(hist16, cnt, meta);
    k_scores<<<dim3((NBOX + SC_ROWS - 1) / SC_ROWS), dim3(256), 0, stream>>>(in, scores, hist16);
    k_scatter<<<dim3((NBOX + 255) / 256), dim3(256), 0, stream>>>(scores, hist16, histsum, off, meta, cnt, unsorted);
    k_rank<<<dim3(CMAX / 256), dim3(256), 0, stream>>>(in, unsorted, off, histsum, meta, sorted, boxes4, vflag);
    k_nms<<<dim3(1), dim3(1024), 0, stream>>>(boxes4, vflag, meta, vincl, cmap, cboxes, kfinal);
    k_output<<<dim3((MAXKEEP * 64 + 255) / 256), dim3(256), 0, stream>>>(in, sorted, meta, kfinal, out);
}

// Round 23
// 106.395 us; speedup vs baseline: 1.2590x; 1.2590x over previous
//
#include <hip/hip_runtime.h>

#define NBOX 300000
#define NFEAT 85
#define NCLS 80
#define NBUCK 4096
#define HSPLIT 16
#define CMAX 8192
#define W64 (CMAX / 64)   // 128 kept-mask words (finalize bookkeeping)
#define MAXKEEP 1000
#define SC_ROWS 64        // k_scores tile rows

typedef unsigned long long u64;
typedef float f4a __attribute__((ext_vector_type(4), aligned(16)));

__device__ __forceinline__ int bucket_of(float s) {
    int b = (int)((s - 0.3f) * (4096.0f / 0.7f));
    if (b < 0) b = 0;
    if (b > NBUCK - 1) b = NBUCK - 1;
    return b;
}

__device__ __forceinline__ bool sup_iou(float by1, float bx1, float by2, float bx2, float ba,
                                        float y1, float x1, float y2, float x2, float area) {
    float iy1 = fmaxf(by1, y1), ix1 = fmaxf(bx1, x1);
    float iy2 = fminf(by2, y2), ix2 = fminf(bx2, x2);
    float inter = fmaxf(iy2 - iy1, 0.0f) * fmaxf(ix2 - ix1, 0.0f);
    float uni = ba + area - inter;
    float iou = (uni > 0.0f) ? inter / uni : 0.0f;
    return iou > 0.5f;
}

__global__ void k_init(unsigned* __restrict__ hist16, unsigned* __restrict__ cnt,
                       int* __restrict__ meta) {
    int i = blockIdx.x * blockDim.x + threadIdx.x;
    if (i < HSPLIT * NBUCK) hist16[i] = 0u;
    if (i < NBUCK) cnt[i] = 0u;
    if (i < 16) meta[i] = 0;
}

// Coalesced staged scores + 16-way split histograms. Full tiles stage via
// global_load_lds width-16 (21 wave-uniform 1KB DMA ops + 64-float tail copy)
// — no VGPR round-trip (G15/T14). Occupancy 7 blocks/CU. Tail block (32 rows)
// keeps the f4a copy path (no OOB DMA). NO completion ticket / fused thresh:
// R16-R20+R22 proved every in-kernel completion/recompute scheme costs
// 25-90us vs the ~6us thresh kernel + gap. Blocks exit with atomics in
// flight; the kernel boundary orders them before k_thresh (proven).
__global__ void __launch_bounds__(256) k_scores(const float* __restrict__ in,
        float* __restrict__ scores, unsigned* __restrict__ hist16) {
    __shared__ float lds[SC_ROWS * NFEAT];  // 21760 B
    int t = threadIdx.x;
    int lane = t & 63, wv = t >> 6;
    long long rbase = (long long)blockIdx.x * SC_ROWS;
    int rows = (NBOX - rbase < SC_ROWS) ? (int)(NBOX - rbase) : SC_ROWS;
    if (rows == SC_ROWS) {
        // DMA stage: 21 x 1KB ops (wave w takes ops w, w+4, ...), covers
        // 5376 floats; tail 64 floats by threads 0-63. All in-bounds.
        const float* src = in + rbase * NFEAT;  // 21760*b bytes: 16B-aligned
        for (int k = wv; k < 21; k += 4)
            __builtin_amdgcn_global_load_lds(
                (const __attribute__((address_space(1))) void*)(src + k * 256 + lane * 4),
                (__attribute__((address_space(3))) void*)&lds[k * 256], 16, 0, 0);
        if (t < 64) lds[5376 + t] = src[5376 + t];
    } else {
        int nfl = rows * NFEAT;
        int nf4 = nfl >> 2;
        const f4a* src4 = (const f4a*)(in + rbase * NFEAT);
        f4a* dst = (f4a*)lds;
        for (int k = t; k < nf4; k += 256) dst[k] = src4[k];
        for (int k = (nf4 << 2) + t; k < nfl; k += 256) lds[k] = in[rbase * NFEAT + k];
    }
    __syncthreads();  // also drains the DMA (vmcnt)
    unsigned* myhist = hist16 + (size_t)(blockIdx.x & (HSPLIT - 1)) * NBUCK;
    int row = t >> 2, part = t & 3;
    if (row < rows) {
        const float* r = lds + row * NFEAT;
        const float* p = r + 5 + 20 * part;
        float mx = p[0];
        #pragma unroll
        for (int j = 1; j < 20; ++j) mx = fmaxf(mx, p[j]);
        mx = fmaxf(mx, __shfl_xor(mx, 1));
        mx = fmaxf(mx, __shfl_xor(mx, 2));
        if (part == 0) {
            float best = r[4] * mx;  // == max(conf*p) exactly (conf>=0, RN monotone)
            scores[rbase + row] = best;
            if (best >= 0.3f) atomicAdd(&myhist[bucket_of(best)], 1u);
        }
    }
}

// Sum split hists; suffix sums; bstar = smallest b with suffix(b) <= CMAX;
// off[b] = suffix(b+1); histsum[b] = bucket size; meta[0]=count, meta[1]=bstar.
__global__ void __launch_bounds__(1024) k_thresh(const unsigned* __restrict__ hist16,
        unsigned* __restrict__ histsum, unsigned* __restrict__ off, int* __restrict__ meta) {
    __shared__ unsigned chunk[1024];
    int t = threadIdx.x;
    unsigned h[4];
    unsigned s = 0;
    #pragma unroll
    for (int j = 0; j < 4; ++j) {
        unsigned v = 0;
        for (int g = 0; g < HSPLIT; ++g) v += hist16[g * NBUCK + t * 4 + j];
        h[j] = v; histsum[t * 4 + j] = v; s += v;
    }
    chunk[t] = s;
    __syncthreads();
    for (int o = 1; o < 1024; o <<= 1) {
        unsigned add = (t + o < 1024) ? chunk[t + o] : 0u;
        __syncthreads();
        chunk[t] += add;
        __syncthreads();
    }
    unsigned after = (t + 1 < 1024) ? chunk[t + 1] : 0u;
    unsigned suf[5];
    suf[4] = after;
    #pragma unroll
    for (int j = 3; j >= 0; --j) suf[j] = suf[j + 1] + h[j];
    #pragma unroll
    for (int j = 0; j < 4; ++j) {
        int b = t * 4 + j;
        off[b] = suf[j] - h[j];
        unsigned sufb = suf[j], sufprev;
        if (b == 0) sufprev = 0xFFFFFFFFu;
        else if (j > 0) sufprev = suf[j - 1];
        else {
            unsigned hprev = 0;
            for (int g = 0; g < HSPLIT; ++g) hprev += hist16[g * NBUCK + b - 1];
            sufprev = sufb + hprev;
        }
        if (sufb <= (unsigned)CMAX && sufprev > (unsigned)CMAX) {
            meta[1] = b;
            meta[0] = (int)sufb;
        }
    }
}

__global__ void k_scatter(const float* __restrict__ scores, const int* __restrict__ meta,
                          const unsigned* __restrict__ off, unsigned* __restrict__ cnt,
                          u64* __restrict__ unsorted) {
    int i = blockIdx.x * blockDim.x + threadIdx.x;
    if (i >= NBOX) return;
    float s = scores[i];
    if (s < 0.3f) return;
    int b = bucket_of(s);
    if (b < meta[1]) return;
    unsigned slot = off[b] + atomicAdd(&cnt[b], 1u);
    if (slot < CMAX)
        unsorted[slot] = ((u64)__float_as_uint(s) << 32) |
                         (u64)(0xFFFFFFFFu - (unsigned)i);
}

// Exact rank within bucket -> fully sorted, deterministic (MULTI-BLOCK: the
// per-candidate bucket-scan loads need cross-CU TLP — R16's 1-block fusion of
// this phase was a 10x regression). Compacts box + validity flag per slot.
__global__ void k_rank(const float* __restrict__ in, const u64* __restrict__ unsorted,
                       const unsigned* __restrict__ off, const unsigned* __restrict__ histsum,
                       const int* __restrict__ meta, u64* __restrict__ sorted,
                       float4* __restrict__ boxes4, unsigned* __restrict__ vflag) {
    int i = blockIdx.x * blockDim.x + threadIdx.x;
    int total = meta[0];
    if (i >= total) return;
    u64 k = unsorted[i];
    float s = __uint_as_float((unsigned)(k >> 32));
    int b = bucket_of(s);
    unsigned base = off[b];
    unsigned n = histsum[b];
    unsigned r = 0;
    for (unsigned u = 0; u < n; ++u) r += (unsorted[base + u] > k) ? 1u : 0u;
    int bi = (int)(0xFFFFFFFFu - (unsigned)(k & 0xFFFFFFFFull));
    const float* p = in + (size_t)bi * NFEAT;
    float4 bx = make_float4(p[0], p[1], p[2], p[3]);  // y1,x1,y2,x2
    sorted[base + r] = k;
    boxes4[base + r] = bx;
    vflag[base + r] = (bx.z > bx.x && bx.w > bx.y) ? 1u : 0u;
}

// Fused NMS (R15 structure — proven):
//  - vscan & finalize use WAVE-LEVEL scans (shfl_up, 2 barriers each)
//  - sweep greedy is Z-GATED: zero-col candidates (suppress nobody) batch-kept
//    in one mask op; serial iterations only for the ~1/block nonzero-col keeps.
// Degenerate boxes (IoU==0 with everything) skip the sweep, always kept.
__global__ void __launch_bounds__(1024) k_nms(const float4* __restrict__ boxes4,
        const unsigned* __restrict__ vflag, int* __restrict__ meta,
        unsigned* __restrict__ vincl, unsigned* __restrict__ cmap,
        float4* __restrict__ cboxes, int* __restrict__ kfinal) {
    __shared__ float4 klist[MAXKEEP + 64];
    __shared__ u64 colmask[64];
    __shared__ u64 pf[16];
    __shared__ u64 vkeptw[W64];
    __shared__ unsigned wsum[16];
    __shared__ int sh_nkept, sh_wlim, sh_stop;
    int t = threadIdx.x;
    int lane = t & 63, wv = t >> 6;
    int total = meta[0];

    if (t < W64) vkeptw[t] = 0ull;
    if (t == 0) { sh_nkept = 0; sh_wlim = 0; sh_stop = 0; }

    // ---- vscan phase (wave-level scan: 2 barriers) ----
    unsigned f[8];
    {
        unsigned run = 0;
        #pragma unroll
        for (int e = 0; e < 8; ++e) {
            int s = t * 8 + e;
            unsigned v = (s < total) ? vflag[s] : 0u;
            run += v;
            f[e] = run;
        }
        unsigned wx = run;
        #pragma unroll
        for (int o = 1; o < 64; o <<= 1) {
            unsigned u = __shfl_up(wx, o);
            if (lane >= o) wx += u;
        }
        if (lane == 63) wsum[wv] = wx;
        __syncthreads();
        if (t < 16) {
            unsigned v = wsum[t];
            #pragma unroll
            for (int o = 1; o < 16; o <<= 1) {
                unsigned u = __shfl_up(v, o);
                if (t >= o) v += u;
            }
            wsum[t] = v;
        }
        __syncthreads();
        unsigned base = ((wv > 0) ? wsum[wv - 1] : 0u) + (wx - run);
        #pragma unroll
        for (int e = 0; e < 8; ++e) {
            int s = t * 8 + e;
            unsigned incl = base + f[e];
            vincl[s] = incl;
            if (s < total && vflag[s]) {
                cmap[incl - 1] = (unsigned)s;
                cboxes[incl - 1] = boxes4[s];
            }
        }
    }
    int nv = (int)wsum[15];
    if (t == 0) meta[3] = nv;
    int nblkv = (nv + 63) >> 6;
    __syncthreads();  // cboxes/cmap visible before sweep

    // ---- sweep phase (16-wave prefilter + col build; Z-gated wave-0 greedy) ----
    for (int w = 0; w < nblkv; ++w) {
        int base = w << 6;
        int c = base + lane;
        float4 mb = (c < nv) ? cboxes[c] : make_float4(0.f, 0.f, 0.f, 0.f);
        float marea = (mb.z - mb.x) * (mb.w - mb.y);
        int cend = (base + 63 < nv - 1) ? (base + 63) : (nv - 1);
        unsigned cm = 0;
        if (wv == 0) cm = cmap[cend];  // issued early, used after barrier
        int nk = sh_nkept;  // stable: post prior-iteration barrier
        // A) prefilter: wave wv covers klist[wv::16]
        bool ok = true;
        for (int k = wv; k < nk; k += 16) {
            float4 b = klist[k];
            float ba = (b.z - b.x) * (b.w - b.y);
            if (sup_iou(b.x, b.y, b.z, b.w, ba, mb.x, mb.y, mb.z, mb.w, marea))
                ok = false;
        }
        u64 pv = __ballot(ok ? 1 : 0);
        if (lane == 0) pf[wv] = pv;
        // B) intra-block cols: wave wv builds rows 4*wv .. 4*wv+3
        #pragma unroll
        for (int r = 0; r < 4; ++r) {
            int i = wv * 4 + r;
            int ii = (base + i < nv) ? (base + i) : 0;  // clamp; garbage cols of
            float4 bi = cboxes[ii];                     // dead rows are never used
            float ba = (bi.z - bi.x) * (bi.w - bi.y);
            bool s = (lane > i) &&
                     sup_iou(bi.x, bi.y, bi.z, bi.w, ba, mb.x, mb.y, mb.z, mb.w, marea);
            u64 bm = __ballot(s ? 1 : 0);
            if (lane == 0) colmask[i] = bm;
        }
        __syncthreads();
        // C) wave 0: Z-gated greedy (zero-col candidates suppress nobody ->
        // batch-kept below the lowest nonzero-col candidate; exact)
        if (wv == 0) {
            int rc = nv - base;
            u64 vm = (rc >= 64) ? ~0ull : ((1ull << rc) - 1ull);
            u64 aliveM = vm;
            #pragma unroll
            for (int q = 0; q < 16; ++q) aliveM &= pf[q];
            u64 col = colmask[lane];
            u64 nzc = __ballot(col != 0ull);
            u64 remaining = aliveM, keptM = 0ull;
            while (remaining) {
                u64 hard = remaining & nzc;
                if (!hard) { keptM |= remaining; break; }
                int ih = __ffsll(hard) - 1;
                u64 below = remaining & ((1ull << ih) - 1ull);  // all zero-col
                keptM |= below | (1ull << ih);
                remaining &= ~(below | (1ull << ih));
                u64 ci = __shfl(col, ih);
                remaining &= ~ci;
            }
            int nk0 = sh_nkept;
            if ((keptM >> lane) & 1ull) {
                int rank = __popcll(keptM & ((1ull << lane) - 1ull));
                klist[nk0 + rank] = mb;
            }
            if (lane == 0) {
                int kp = __popcll(keptM);
                vkeptw[w] = keptM;
                sh_nkept = nk0 + kp;
                sh_wlim = w + 1;
                // merged kept through slot cm: invalids (cm-cend) + valid-kept
                if ((int)cm - cend + nk0 + kp >= MAXKEEP) sh_stop = 1;
            }
        }
        __syncthreads();
        if (sh_stop) break;  // uniform
    }
    int wlim = sh_wlim;

    // ---- finalize (wave-level scan: 2 barriers) ----
    {
        unsigned run = 0;
        #pragma unroll
        for (int e = 0; e < 8; ++e) {
            int s = t * 8 + e;
            unsigned kept = 0u;
            if (s < total) {
                if (!vflag[s]) kept = 1u;
                else {
                    unsigned cc = vincl[s] - 1u;
                    int w = (int)(cc >> 6);
                    if (w < wlim && ((vkeptw[w] >> (cc & 63u)) & 1ull)) kept = 1u;
                }
            }
            run += kept;
            f[e] = run;
        }
        unsigned wx = run;
        #pragma unroll
        for (int o = 1; o < 64; o <<= 1) {
            unsigned u = __shfl_up(wx, o);
            if (lane >= o) wx += u;
        }
        __syncthreads();  // wsum reuse: vscan values dead
        if (lane == 63) wsum[wv] = wx;
        __syncthreads();
        if (t < 16) {
            unsigned v = wsum[t];
            #pragma unroll
            for (int o = 1; o < 16; o <<= 1) {
                unsigned u = __shfl_up(v, o);
                if (t >= o) v += u;
            }
            wsum[t] = v;
        }
        __syncthreads();
        unsigned base = ((wv > 0) ? wsum[wv - 1] : 0u) + (wx - run);
        #pragma unroll
        for (int e = 0; e < 8; ++e) {
            int s = t * 8 + e;
            unsigned kept = 0u;
            if (s < total) {
                if (!vflag[s]) kept = 1u;
                else {
                    unsigned cc = vincl[s] - 1u;
                    int w = (int)(cc >> 6);
                    if (w < wlim && ((vkeptw[w] >> (cc & 63u)) & 1ull)) kept = 1u;
                }
            }
            unsigned incl = base + f[e];
            if (kept && incl <= (unsigned)MAXKEEP) kfinal[incl - 1] = s;
        }
        if (t == 0) {
            unsigned tot = wsum[15];
            meta[2] = (int)(tot < (unsigned)MAXKEEP ? tot : (unsigned)MAXKEEP);
        }
    }
}

// One wave per output row (MULTI-BLOCK): butterfly argmax, strict-greater /
// lower-index tiebreak (== jnp.argmax first occurrence).
__global__ void __launch_bounds__(256) k_output(const float* __restrict__ in,
        const u64* __restrict__ gkeys, const int* __restrict__ meta,
        const int* __restrict__ kfinal, float* __restrict__ out) {
    int gw = (blockIdx.x * blockDim.x + threadIdx.x) >> 6;
    int lane = threadIdx.x & 63;
    if (gw >= MAXKEEP) return;
    int kc = meta[2];
    if (gw < kc) {
        int pos = kfinal[gw];
        u64 key = gkeys[pos];
        int bi = (int)(0xFFFFFFFFu - (unsigned)(key & 0xFFFFFFFFull));
        const float* row = in + (size_t)bi * NFEAT;
        float conf = row[4];
        float v0 = (lane < NCLS) ? conf * row[5 + lane] : -1.0f;
        float v1 = (lane < NCLS - 64) ? conf * row[5 + 64 + lane] : -1.0f;
        float bv = (v1 > v0) ? v1 : v0;
        int bix = (v1 > v0) ? (64 + lane) : lane;
        #pragma unroll
        for (int o = 1; o < 64; o <<= 1) {
            float ov = __shfl_xor(bv, o);
            int oi = __shfl_xor(bix, o);
            if (ov > bv || (ov == bv && oi < bix)) { bv = ov; bix = oi; }
        }
        float wv = 0.f;
        if (lane < 4) wv = row[lane];
        else if (lane == 4) wv = (float)bix;
        else wv = bv;
        if (lane < 6) out[gw * 6 + lane] = wv;
    } else {
        if (lane < 6) out[gw * 6 + lane] = 0.f;
    }
}

extern "C" void kernel_launch(void* const* d_in, const int* in_sizes, int n_in,
                              void* d_out, int out_size, void* d_ws, size_t ws_size,
                              hipStream_t stream) {
    const float* in = (const float*)d_in[0];
    float* out = (float*)d_out;
    char* ws = (char*)d_ws;
    // ws layout (bytes):
    //   [0, 65536)           sorted   u64[8192]
    //   [65536, 65600)       meta     i32[16] {0:total,1:bstar,2:kc,3:nvalid}
    //   [65600, 69696)       kfinal   i32[1024]
    //   [69696, 102464)      vflag    u32[8192]
    //   [102464, 135232)     vincl    u32[8192]
    //   [135232, 168000)     cmap     u32[8192]
    //   [168000, 300096)     cboxes   float4[8256]  (+64 pad)
    //   [300096, 431168)     boxes4   float4[8192]
    //   [431168, 1631168)    scores   f32[300000]
    //   [1631168, 1893312)   hist16   u32[16*4096]
    //   [1893312, 1909696)   histsum  u32[4096]
    //   [1909696, 1926080)   cnt      u32[4096]
    //   [1926080, 1942464)   off      u32[4096]
    //   [1942464, 2008000)   unsorted u64[8192]
    u64* sorted = (u64*)(ws);
    int* meta = (int*)(ws + 65536);
    int* kfinal = (int*)(ws + 65600);
    unsigned* vflag = (unsigned*)(ws + 69696);
    unsigned* vincl = (unsigned*)(ws + 102464);
    unsigned* cmap = (unsigned*)(ws + 135232);
    float4* cboxes = (float4*)(ws + 168000);
    float4* boxes4 = (float4*)(ws + 300096);
    float* scores = (float*)(ws + 431168);
    unsigned* hist16 = (unsigned*)(ws + 1631168);
    unsigned* histsum = (unsigned*)(ws + 1893312);
    unsigned* cnt = (unsigned*)(ws + 1909696);
    unsigned* off = (unsigned*)(ws + 1926080);
    u64* unsorted = (u64*)(ws + 1942464);

    k_init<<<dim3(256), dim3(256), 0, stream>>>(hist16, cnt, meta);
    k_scores<<<dim3((NBOX + SC_ROWS - 1) / SC_ROWS), dim3(256), 0, stream>>>(in, scores, hist16);
    k_thresh<<<dim3(1), dim3(1024), 0, stream>>>(hist16, histsum, off, meta);
    k_scatter<<<dim3((NBOX + 255) / 256), dim3(256), 0, stream>>>(scores, meta, off, cnt, unsorted);
    k_rank<<<dim3(CMAX / 256), dim3(256), 0, stream>>>(in, unsorted, off, histsum, meta, sorted, boxes4, vflag);
    k_nms<<<dim3(1), dim3(1024), 0, stream>>>(boxes4, vflag, meta, vincl, cmap, cboxes, kfinal);
    k_output<<<dim3((MAXKEEP * 64 + 255) / 256), dim3(256), 0, stream>>>(in, sorted, meta, kfinal, out);
}